// Round 1
// baseline (79.267 us; speedup 1.0000x reference)
//
#include <hip/hip_runtime.h>
#include <hip/hip_bf16.h>

// Problem constants (fixed by setup_inputs)
#define B 16
#define L 1024
#define D 512
#define T 8192            // mel_max_length
#define D4 (D / 4)        // 128 float4 per row

// Kernel 1: per-batch inclusive scan of duration_tokens -> csum (int32) in ws.
// One block of 1024 threads per batch.
__global__ __launch_bounds__(1024) void lr_scan_kernel(const int* __restrict__ dur,
                                                       int* __restrict__ csum) {
    const int b   = blockIdx.x;
    const int tid = threadIdx.x;
    const int lane = tid & 63;
    const int wid  = tid >> 6;          // 16 waves

    int s = dur[b * L + tid];

    // wave-level inclusive scan (wave = 64 lanes)
    #pragma unroll
    for (int off = 1; off < 64; off <<= 1) {
        int n = __shfl_up(s, off, 64);
        if (lane >= off) s += n;
    }

    __shared__ int wsum[16];
    if (lane == 63) wsum[wid] = s;
    __syncthreads();

    if (wid == 0 && lane < 16) {
        int w = wsum[lane];
        #pragma unroll
        for (int off = 1; off < 16; off <<= 1) {
            int n = __shfl_up(w, off, 64);
            if (lane >= off) w += n;
        }
        wsum[lane] = w;
    }
    __syncthreads();

    int offset = (wid > 0) ? wsum[wid - 1] : 0;
    csum[b * L + tid] = s + offset;
}

// Kernel 2: one block per output row (b, t). 128 threads, each copies one float4.
// idx = upper_bound(csum[b], t)  (== searchsorted(side='right'));  zero if t >= total.
__global__ __launch_bounds__(128) void lr_gather_kernel(const float* __restrict__ x,
                                                        const int* __restrict__ csum,
                                                        float* __restrict__ out) {
    const int blk = blockIdx.x;
    const int b = blk >> 13;            // / 8192
    const int t = blk & (T - 1);

    const int* __restrict__ c = csum + b * L;
    const int total = c[L - 1];

    float4* __restrict__ orow = reinterpret_cast<float4*>(out) + (size_t)blk * D4;

    if (t >= total) {
        orow[threadIdx.x] = make_float4(0.f, 0.f, 0.f, 0.f);
        return;
    }

    // upper_bound over 1024 sorted ints (identical across threads; L1-resident)
    int lo = 0, hi = L;
    while (lo < hi) {
        int mid = (lo + hi) >> 1;
        if (c[mid] <= t) lo = mid + 1; else hi = mid;
    }
    int idx = lo < (L - 1) ? lo : (L - 1);

    const float4* __restrict__ xrow =
        reinterpret_cast<const float4*>(x) + ((size_t)b * L + idx) * D4;
    orow[threadIdx.x] = xrow[threadIdx.x];
}

extern "C" void kernel_launch(void* const* d_in, const int* in_sizes, int n_in,
                              void* d_out, int out_size, void* d_ws, size_t ws_size,
                              hipStream_t stream) {
    const float* x   = (const float*)d_in[0];
    const int*   dur = (const int*)d_in[1];
    float*       out = (float*)d_out;
    int*         csum = (int*)d_ws;     // B*L ints = 64 KB

    lr_scan_kernel<<<B, 1024, 0, stream>>>(dur, csum);
    lr_gather_kernel<<<B * T, 128, 0, stream>>>(x, csum, out);
}

// Round 2
// 60.409 us; speedup vs baseline: 1.3122x; 1.3122x over previous
//
#include <hip/hip_runtime.h>
#include <hip/hip_bf16.h>

// Problem constants (fixed by setup_inputs)
#define B 16
#define L 1024
#define D 512
#define T 8192            // mel_max_length
#define D4 (D / 4)        // 128 float4 per row
#define ROWS_PER_BLK 8

// ---------------- Path A: scan+scatter -> idx table, then indirect memcpy ---

// One block (1024 threads) per batch: inclusive scan of durations, then each
// thread scatters its source index (b*L + l) into idx[b][start..end), and the
// block fills the tail [total, T) with -1.
__global__ __launch_bounds__(1024) void lr_scan_scatter(const int* __restrict__ dur,
                                                        int* __restrict__ idx) {
    const int b    = blockIdx.x;
    const int tid  = threadIdx.x;
    const int lane = tid & 63;
    const int wid  = tid >> 6;          // 16 waves

    const int d = dur[b * L + tid];
    int s = d;
    #pragma unroll
    for (int off = 1; off < 64; off <<= 1) {
        int n = __shfl_up(s, off, 64);
        if (lane >= off) s += n;
    }

    __shared__ int wsum[16];
    if (lane == 63) wsum[wid] = s;
    __syncthreads();

    if (tid < 16) {                     // all in wave 0; lanes <16 active
        int w = wsum[tid];
        #pragma unroll
        for (int off = 1; off < 16; off <<= 1) {
            int n = __shfl_up(w, off, 64);
            if (tid >= off) w += n;
        }
        wsum[tid] = w;
    }
    __syncthreads();

    const int incl  = s + (wid ? wsum[wid - 1] : 0);   // inclusive csum
    const int start = incl - d;
    const int src   = b * L + tid;
    int* __restrict__ ib = idx + b * T;

    for (int t = start; t < incl; ++t) ib[t] = src;    // <=7 writes/thread

    const int total = wsum[15];
    for (int t = total + tid; t < T; t += 1024) ib[t] = -1;
}

// 256 threads/block, 8 rows/block. Two 128-thread row-groups; idx loads for
// all 4 rows of a group issued upfront for ILP, then 4 independent copies.
__global__ __launch_bounds__(256) void lr_gather2(const float* __restrict__ x,
                                                  const int* __restrict__ idx,
                                                  float* __restrict__ out) {
    const int lane = threadIdx.x & (D4 - 1);
    const int sub  = threadIdx.x >> 7;                 // 0 or 1
    const int row0 = blockIdx.x * ROWS_PER_BLK + sub;

    int ids[ROWS_PER_BLK / 2];
    #pragma unroll
    for (int i = 0; i < ROWS_PER_BLK / 2; ++i)
        ids[i] = idx[row0 + 2 * i];

    const float4* __restrict__ x4 = reinterpret_cast<const float4*>(x);
    float4*       __restrict__ o4 = reinterpret_cast<float4*>(out);

    #pragma unroll
    for (int i = 0; i < ROWS_PER_BLK / 2; ++i) {
        const int row = row0 + 2 * i;
        const int id  = ids[i] < 0 ? 0 : ids[i];       // clamp: row 0 stays hot in L1
        float4 v = x4[(size_t)id * D4 + lane];
        if (ids[i] < 0) v = make_float4(0.f, 0.f, 0.f, 0.f);
        o4[(size_t)row * D4 + lane] = v;
    }
}

// ---------------- Path B (fallback if ws too small): round-1 kernels --------

__global__ __launch_bounds__(1024) void lr_scan_kernel(const int* __restrict__ dur,
                                                       int* __restrict__ csum) {
    const int b   = blockIdx.x;
    const int tid = threadIdx.x;
    const int lane = tid & 63;
    const int wid  = tid >> 6;

    int s = dur[b * L + tid];
    #pragma unroll
    for (int off = 1; off < 64; off <<= 1) {
        int n = __shfl_up(s, off, 64);
        if (lane >= off) s += n;
    }
    __shared__ int wsum[16];
    if (lane == 63) wsum[wid] = s;
    __syncthreads();
    if (wid == 0 && lane < 16) {
        int w = wsum[lane];
        #pragma unroll
        for (int off = 1; off < 16; off <<= 1) {
            int n = __shfl_up(w, off, 64);
            if (lane >= off) w += n;
        }
        wsum[lane] = w;
    }
    __syncthreads();
    int offset = (wid > 0) ? wsum[wid - 1] : 0;
    csum[b * L + tid] = s + offset;
}

__global__ __launch_bounds__(128) void lr_gather_kernel(const float* __restrict__ x,
                                                        const int* __restrict__ csum,
                                                        float* __restrict__ out) {
    const int blk = blockIdx.x;
    const int b = blk >> 13;
    const int t = blk & (T - 1);

    const int* __restrict__ c = csum + b * L;
    const int total = c[L - 1];

    float4* __restrict__ orow = reinterpret_cast<float4*>(out) + (size_t)blk * D4;
    if (t >= total) {
        orow[threadIdx.x] = make_float4(0.f, 0.f, 0.f, 0.f);
        return;
    }
    int lo = 0, hi = L;
    while (lo < hi) {
        int mid = (lo + hi) >> 1;
        if (c[mid] <= t) lo = mid + 1; else hi = mid;
    }
    int idx = lo < (L - 1) ? lo : (L - 1);
    const float4* __restrict__ xrow =
        reinterpret_cast<const float4*>(x) + ((size_t)b * L + idx) * D4;
    orow[threadIdx.x] = xrow[threadIdx.x];
}

// ---------------------------------------------------------------------------

extern "C" void kernel_launch(void* const* d_in, const int* in_sizes, int n_in,
                              void* d_out, int out_size, void* d_ws, size_t ws_size,
                              hipStream_t stream) {
    const float* x   = (const float*)d_in[0];
    const int*   dur = (const int*)d_in[1];
    float*       out = (float*)d_out;

    if (ws_size >= (size_t)B * T * sizeof(int)) {
        int* idx = (int*)d_ws;                           // B*T ints = 512 KB
        lr_scan_scatter<<<B, 1024, 0, stream>>>(dur, idx);
        lr_gather2<<<B * T / ROWS_PER_BLK, 256, 0, stream>>>(x, idx, out);
    } else {
        int* csum = (int*)d_ws;                          // B*L ints = 64 KB
        lr_scan_kernel<<<B, 1024, 0, stream>>>(dur, csum);
        lr_gather_kernel<<<B * T, 128, 0, stream>>>(x, csum, out);
    }
}

// Round 3
// 55.534 us; speedup vs baseline: 1.4274x; 1.0878x over previous
//
#include <hip/hip_runtime.h>
#include <hip/hip_bf16.h>

// Problem constants (fixed by setup_inputs)
#define B 16
#define L 1024
#define D 512
#define T 8192            // mel_max_length
#define D4 (D / 4)        // 128 float4 per row
#define ROWS_PER_BLK 8
#define NBLK ((B * T) / ROWS_PER_BLK)   // 16384, divisible by 8

typedef float f4 __attribute__((ext_vector_type(4)));

// ---------------- Kernel 1: scan + scatter -> idx table ---------------------
// One block (1024 threads) per batch: inclusive scan of durations, then each
// thread scatters its source index (b*L + l) into idx[b][start..end), and the
// block fills the tail [total, T) with -1.
__global__ __launch_bounds__(1024) void lr_scan_scatter(const int* __restrict__ dur,
                                                        int* __restrict__ idx) {
    const int b    = blockIdx.x;
    const int tid  = threadIdx.x;
    const int lane = tid & 63;
    const int wid  = tid >> 6;          // 16 waves

    const int d = dur[b * L + tid];
    int s = d;
    #pragma unroll
    for (int off = 1; off < 64; off <<= 1) {
        int n = __shfl_up(s, off, 64);
        if (lane >= off) s += n;
    }

    __shared__ int wsum[16];
    if (lane == 63) wsum[wid] = s;
    __syncthreads();

    if (tid < 16) {                     // all in wave 0; lanes <16 active
        int w = wsum[tid];
        #pragma unroll
        for (int off = 1; off < 16; off <<= 1) {
            int n = __shfl_up(w, off, 64);
            if (tid >= off) w += n;
        }
        wsum[tid] = w;
    }
    __syncthreads();

    const int incl  = s + (wid ? wsum[wid - 1] : 0);   // inclusive csum
    const int start = incl - d;
    const int src   = b * L + tid;
    int* __restrict__ ib = idx + b * T;

    for (int t = start; t < incl; ++t) ib[t] = src;    // <=7 writes/thread

    const int total = wsum[15];
    for (int t = total + tid; t < T; t += 1024) ib[t] = -1;
}

// ---------------- Kernel 2: indirect row memcpy ------------------------------
// 256 threads/block, 8 rows/block. XCD-chunked swizzle: each XCD gets a
// contiguous 2048-block chunk (= 2 batches = 4 MB x-slice, fits its 4 MB L2).
// Non-temporal stores keep the 268 MB write stream from evicting x out of L2.
__global__ __launch_bounds__(256) void lr_gather2(const float* __restrict__ x,
                                                  const int* __restrict__ idx,
                                                  float* __restrict__ out) {
    int bid = blockIdx.x;
    bid = (bid & 7) * (NBLK / 8) + (bid >> 3);         // XCD-chunked swizzle

    const int lane = threadIdx.x & (D4 - 1);
    const int sub  = threadIdx.x >> 7;                 // 0 or 1
    const int row0 = bid * ROWS_PER_BLK + sub;

    int ids[ROWS_PER_BLK / 2];
    #pragma unroll
    for (int i = 0; i < ROWS_PER_BLK / 2; ++i)
        ids[i] = idx[row0 + 2 * i];

    const f4* __restrict__ x4 = reinterpret_cast<const f4*>(x);
    f4*       __restrict__ o4 = reinterpret_cast<f4*>(out);

    #pragma unroll
    for (int i = 0; i < ROWS_PER_BLK / 2; ++i) {
        const int row = row0 + 2 * i;
        const int id  = ids[i] < 0 ? 0 : ids[i];       // clamp: row 0 stays hot in L2
        f4 v = x4[(size_t)id * D4 + lane];
        if (ids[i] < 0) v = (f4)(0.f);
        __builtin_nontemporal_store(v, &o4[(size_t)row * D4 + lane]);
    }
}

// ---------------- Path B (fallback if ws too small): round-1 kernels --------

__global__ __launch_bounds__(1024) void lr_scan_kernel(const int* __restrict__ dur,
                                                       int* __restrict__ csum) {
    const int b   = blockIdx.x;
    const int tid = threadIdx.x;
    const int lane = tid & 63;
    const int wid  = tid >> 6;

    int s = dur[b * L + tid];
    #pragma unroll
    for (int off = 1; off < 64; off <<= 1) {
        int n = __shfl_up(s, off, 64);
        if (lane >= off) s += n;
    }
    __shared__ int wsum[16];
    if (lane == 63) wsum[wid] = s;
    __syncthreads();
    if (wid == 0 && lane < 16) {
        int w = wsum[lane];
        #pragma unroll
        for (int off = 1; off < 16; off <<= 1) {
            int n = __shfl_up(w, off, 64);
            if (lane >= off) w += n;
        }
        wsum[lane] = w;
    }
    __syncthreads();
    int offset = (wid > 0) ? wsum[wid - 1] : 0;
    csum[b * L + tid] = s + offset;
}

__global__ __launch_bounds__(128) void lr_gather_kernel(const float* __restrict__ x,
                                                        const int* __restrict__ csum,
                                                        float* __restrict__ out) {
    const int blk = blockIdx.x;
    const int b = blk >> 13;
    const int t = blk & (T - 1);

    const int* __restrict__ c = csum + b * L;
    const int total = c[L - 1];

    float4* __restrict__ orow = reinterpret_cast<float4*>(out) + (size_t)blk * D4;
    if (t >= total) {
        orow[threadIdx.x] = make_float4(0.f, 0.f, 0.f, 0.f);
        return;
    }
    int lo = 0, hi = L;
    while (lo < hi) {
        int mid = (lo + hi) >> 1;
        if (c[mid] <= t) lo = mid + 1; else hi = mid;
    }
    int idx = lo < (L - 1) ? lo : (L - 1);
    const float4* __restrict__ xrow =
        reinterpret_cast<const float4*>(x) + ((size_t)b * L + idx) * D4;
    orow[threadIdx.x] = xrow[threadIdx.x];
}

// ---------------------------------------------------------------------------

extern "C" void kernel_launch(void* const* d_in, const int* in_sizes, int n_in,
                              void* d_out, int out_size, void* d_ws, size_t ws_size,
                              hipStream_t stream) {
    const float* x   = (const float*)d_in[0];
    const int*   dur = (const int*)d_in[1];
    float*       out = (float*)d_out;

    if (ws_size >= (size_t)B * T * sizeof(int)) {
        int* idx = (int*)d_ws;                           // B*T ints = 512 KB
        lr_scan_scatter<<<B, 1024, 0, stream>>>(dur, idx);
        lr_gather2<<<NBLK, 256, 0, stream>>>(x, idx, out);
    } else {
        int* csum = (int*)d_ws;                          // B*L ints = 64 KB
        lr_scan_kernel<<<B, 1024, 0, stream>>>(dur, csum);
        lr_gather_kernel<<<B * T, 128, 0, stream>>>(x, csum, out);
    }
}